// Round 12
// baseline (114.469 us; speedup 1.0000x reference)
//
#include <hip/hip_runtime.h>

// R20: LANE-GEOMETRY RESTRUCTURE. 8 lanes/ray x 8 samples/lane (was 16x4),
//   32 rays per 256-thr block. Rationale: R19 calibrated the kernel as
//   VALU-issue-bound at ~0.027us per lane-op; ~27% of the ~580 ops/lane are
//   FIXED per-lane (o/d loads+addr, a/b2, scans, T/rtot, setup). Halving
//   lanes/ray halves the per-ray fixed cost: est -13% VALU = -2us.
//   Scans confined to 8-lane groups inside 16-lane DPP rows: shr:1/2/4
//   pollute row-lanes 8..11 from the other ray -> identity-cndmask on
//   (L8==0)/(L8<2)/(L8<4). prev-cr and Mex/Sex/Pex exclusives likewise.
//   Lane-7 polluted P never crosses (audited); z8/s8 = next ray's real data,
//   masked like the old L15 case. +(1.0000001f-alpha) fold (rel 2e-8).
// R19: exp2 fold + uniform-dz — WIN 114.54->113.78 (matched op-count model).
// R17/R18: multipass diagnostics: VALUBusy 83%, VGPR 28, FETCH 34.8MB,
//   LDS conflicts minor => VALU-issue-bound; occupancy/memory not limiting.
// R8/R9: inverse scatter; fused affine scan.

template<int CTRL, int RM>
__device__ __forceinline__ float dpp_movf(float old, float x) {
    return __int_as_float(__builtin_amdgcn_update_dpp(
        __float_as_int(old), __float_as_int(x), CTRL, RM, 0xF, false));
}
template<int CTRL, int RM>
__device__ __forceinline__ int dpp_movi(int old, int x) {
    return __builtin_amdgcn_update_dpp(old, x, CTRL, RM, 0xF, false);
}
// row_shr:N = 0x110|N (16-lane rows), wave_shl:1 = 0x130 (validated R1-R19).
__device__ __forceinline__ float fast_rcp(float x) { return __builtin_amdgcn_rcpf(x); }
__device__ __forceinline__ float bperm(float x, int srclane) {
    return __int_as_float(__builtin_amdgcn_ds_bpermute(srclane << 2, __float_as_int(x)));
}

__global__ __launch_bounds__(256, 4) void neus_upsample_kernel(
    const float* __restrict__ rays_o,
    const float* __restrict__ rays_d,
    const float* __restrict__ z_vals,
    const float* __restrict__ sdf,
    const int*   __restrict__ inv_s_ptr,
    float*       __restrict__ out,
    int n_rays)
{
    __shared__ float cdf_s[32][68];   // cdf per block-ray slot (stride-padded)
    __shared__ int   mark_s[32][64];  // scatter slots

    const int tid  = threadIdx.x;
    const int lane = tid & 63;
    const int L8   = lane & 7;        // lane within ray
    const int slot = tid >> 3;        // block ray slot 0..31
    const int ray  = blockIdx.x * 32 + slot;
    if (ray >= n_rays) return;        // n_rays % 32 == 0

    // boundary masks: 8-lane ray groups inside 16-lane DPP rows
    const bool m0  = (L8 == 0);
    const bool m01 = (L8 <  2);
    const bool m03 = (L8 <  4);

    // init early - LDS store latency hides under the exp chain below.
    *(int4*)(&mark_s[slot][8 * L8])     = make_int4(0, 0, 0, 0);
    *(int4*)(&mark_s[slot][8 * L8 + 4]) = make_int4(0, 0, 0, 0);

    const float inv_s = (float)inv_s_ptr[0];
    const float s2 = -1.4426950408889634f * inv_s;   // exp2 scale (R19)

    // ---- loads: 8 consecutive samples per lane ----
    const float4 zc0 = *(const float4*)(z_vals + ray * 64 + 8 * L8);
    const float4 zc1 = *(const float4*)(z_vals + ray * 64 + 8 * L8 + 4);
    const float4 sc0 = *(const float4*)(sdf    + ray * 64 + 8 * L8);
    const float4 sc1 = *(const float4*)(sdf    + ray * 64 + 8 * L8 + 4);
    const float ox = rays_o[ray*3+0], oy = rays_o[ray*3+1], oz = rays_o[ray*3+2];
    const float dx = rays_d[ray*3+0], dy = rays_d[ray*3+1], dz_ = rays_d[ray*3+2];
    const float a  = ox*ox + oy*oy + oz*oz;
    const float b2 = 2.0f * (ox*dx + oy*dy + oz*dz_);

    // sample 8*L8+8 from lane+1 (wave_shl:1). At L8==7 this is the NEXT
    // ray's sample 0 (real finite data) -> interval 63 masked below, exactly
    // like the old L==15 case. Lane 63: bound_ctrl keeps old (finite).
    const float z8 = dpp_movf<0x130, 0xF>(zc0.x, zc0.x);
    const float s8 = dpp_movf<0x130, 0xF>(sc0.x, sc0.x);

    // scan-independent; LDS-pipe latency overlaps the exp chain.
    const float z0  = bperm(zc0.x, lane & 56);
    const float z63 = bperm(zc1.w, lane | 7);
    const float h   = (z63 - z0) * (1.0f / 63.0f);

    // uniform interval width (z_vals affine in index) — R19a
    const float rden = fast_rcp(h + 1e-5f);
    const float hd_c = 0.5f * h;

    const float zv[9] = {zc0.x, zc0.y, zc0.z, zc0.w, zc1.x, zc1.y, zc1.z, zc1.w, z8};
    const float sv[9] = {sc0.x, sc0.y, sc0.z, sc0.w, sc1.x, sc1.y, sc1.z, sc1.w, s8};

    // ---- inside-sphere predicates (exact z; discontinuous) ----
    float insf[8];
    {
        float r2a = fmaf(zv[0], zv[0] + b2, a);
        #pragma unroll
        for (int e = 0; e < 8; ++e) {
            const float r2b = fmaf(zv[e+1], zv[e+1] + b2, a);
            insf[e] = (fminf(r2a, r2b) < 1.0f) ? 1.0f : 0.0f;
            r2a = r2b;
        }
    }

    float cr[8];
    #pragma unroll
    for (int e = 0; e < 8; ++e)
        cr[e] = (sv[e+1] - sv[e]) * rden;

    // prev-interval cos: element 7 of lane-1; 0 at ray start.
    // row_shr:1 gives row-lane 8 the other ray's cr[7] -> mask via m0.
    float prev = dpp_movf<0x111, 0xF>(0.0f, cr[7]);
    prev = m0 ? 0.0f : prev;

    // ---- fused sigmoid/alpha/weight loop ----
    float t_part[8];
    float tsum = 0.0f, prun = 1.0f;
    #pragma unroll
    for (int e = 0; e < 8; ++e) {
        float cosv = fminf(prev, cr[e]); prev = cr[e];
        cosv = fminf(fmaxf(cosv, -1000.0f), 0.0f) * insf[e];
        const float mid = 0.5f * (sv[e] + sv[e+1]);
        const float pe  = fmaf(-cosv, hd_c, mid);
        const float ne  = fmaf( cosv, hd_c, mid);
        const float pcf = fast_rcp(1.0f + __builtin_amdgcn_exp2f(pe * s2));
        const float ncf = fast_rcp(1.0f + __builtin_amdgcn_exp2f(ne * s2));
        const float alpha = (pcf - ncf + 1e-5f) * fast_rcp(pcf + 1e-5f);
        float awe = alpha * prun;                 // alpha * exclusive-trans
        if (e == 7) awe = (L8 == 7) ? 0.0f : awe; // interval 63 doesn't exist
        t_part[e] = tsum;
        tsum += awe;
        prun *= (1.0000001f - alpha);             // (1-alpha+1e-7) folded
    }

    // ---- fused affine scan over the 8-lane ray group (3 steps) ----
    // (P,S) o (P',S') = (P*P', S + P*S'); identity (1,0). Boundary lanes
    // (row-lane 8..) receive other-ray data -> cndmask to identity.
    float P = prun, S = tsum;
    {
        float Psh, Ssh;
        Psh = dpp_movf<0x111,0xF>(1.0f, P); Ssh = dpp_movf<0x111,0xF>(0.0f, S);
        Psh = m0  ? 1.0f : Psh;  Ssh = m0  ? 0.0f : Ssh;
        S = fmaf(Psh, S, Ssh); P *= Psh;
        Psh = dpp_movf<0x112,0xF>(1.0f, P); Ssh = dpp_movf<0x112,0xF>(0.0f, S);
        Psh = m01 ? 1.0f : Psh;  Ssh = m01 ? 0.0f : Ssh;
        S = fmaf(Psh, S, Ssh); P *= Psh;
        Psh = dpp_movf<0x114,0xF>(1.0f, P); Ssh = dpp_movf<0x114,0xF>(0.0f, S);
        Psh = m03 ? 1.0f : Psh;  Ssh = m03 ? 0.0f : Ssh;
        S = fmaf(Psh, S, Ssh); P *= Psh;
    }
    float Sex = dpp_movf<0x111, 0xF>(0.0f, S);  // sum over lanes < L8
    float Pex = dpp_movf<0x111, 0xF>(1.0f, P);  // transmittance into lane
    Sex = m0 ? 0.0f : Sex;
    Pex = m0 ? 1.0f : Pex;

    const float T    = fmaf(63.0f, 1e-5f, bperm(S, lane | 7)); // + 63 offsets
    const float rtot = fast_rcp(T);

    // ---- cdf entries C[8L8..8L8+7]: (Sex + Pex*t_part[e] + k*1e-5)/T ----
    const float kbase = (float)(8 * L8);
    const float Sk    = fmaf(kbase, 1e-5f, Sex);
    float cv[8];
    #pragma unroll
    for (int e = 0; e < 8; ++e)
        cv[e] = (fmaf(Pex, t_part[e], Sk) + (float)e * 1e-5f) * rtot;
    *(float4*)(&cdf_s[slot][8 * L8])     = make_float4(cv[0], cv[1], cv[2], cv[3]);
    *(float4*)(&cdf_s[slot][8 * L8 + 4]) = make_float4(cv[4], cv[5], cv[6], cv[7]);
    __builtin_amdgcn_wave_barrier();   // order: init+cdf before scatter

    // ---- scatter: entry j covers slots k >= ceil(64*C_j - 0.5) ----
    #pragma unroll
    for (int e = 0; e < 8; ++e) {
        const int kj = (int)ceilf(fmaf(64.0f, cv[e], -0.5f));
        if (kj < 64) atomicMax(&mark_s[slot][kj], 8 * L8 + e);
    }
    __builtin_amdgcn_wave_barrier();   // order: scatter before gather

    // ---- inclusive max-scan over the 64 slots ----
    const int4 ma = *(const int4*)(&mark_s[slot][8 * L8]);
    const int4 mb = *(const int4*)(&mark_s[slot][8 * L8 + 4]);
    int iv[8];
    iv[0] = ma.x;
    iv[1] = max(iv[0], ma.y);
    iv[2] = max(iv[1], ma.z);
    iv[3] = max(iv[2], ma.w);
    iv[4] = max(iv[3], mb.x);
    iv[5] = max(iv[4], mb.y);
    iv[6] = max(iv[5], mb.z);
    iv[7] = max(iv[6], mb.w);

    int ms = iv[7], t;
    t = dpp_movi<0x111, 0xF>(0, ms); t = m0  ? 0 : t; ms = max(ms, t);
    t = dpp_movi<0x112, 0xF>(0, ms); t = m01 ? 0 : t; ms = max(ms, t);
    t = dpp_movi<0x114, 0xF>(0, ms); t = m03 ? 0 : t; ms = max(ms, t);
    int Mex = dpp_movi<0x111, 0xF>(0, ms);   // max over lanes < L8
    Mex = m0 ? 0 : Mex;

    // ---- interpolation: 2 LDS reads per query ----
    const float* cp = cdf_s[slot];
    float ov[8];
    #pragma unroll
    for (int e = 0; e < 8; ++e) {
        const int   b  = min(max(Mex, iv[e]), 62);
        const float u  = fmaf(kbase + (float)e, 0.015625f, 0.0078125f);
        const float cb = cp[b];
        const float ca = cp[b + 1];
        float gap = ca - cb;
        gap = (gap < 1e-5f) ? 1.0f : gap;
        const float tt = (u - cb) * fast_rcp(gap);
        ov[e] = fmaf((float)b + tt, h, z0);   // z0 + h*(below + t)
    }
    *(float4*)(out + ray * 64 + 8 * L8)     = make_float4(ov[0], ov[1], ov[2], ov[3]);
    *(float4*)(out + ray * 64 + 8 * L8 + 4) = make_float4(ov[4], ov[5], ov[6], ov[7]);
}

extern "C" void kernel_launch(void* const* d_in, const int* in_sizes, int n_in,
                              void* d_out, int out_size, void* d_ws, size_t ws_size,
                              hipStream_t stream) {
    const float* rays_o = (const float*)d_in[0];
    const float* rays_d = (const float*)d_in[1];
    const float* z_vals = (const float*)d_in[2];
    const float* sdf    = (const float*)d_in[3];
    // d_in[4] = n_importance (== 64, hardcoded)
    const int*   inv_s  = (const int*)d_in[5];
    float* out = (float*)d_out;

    const int n_rays = in_sizes[0] / 3;          // 131072
    const int blocks = (n_rays + 31) / 32;       // 32 rays per 256-thr block

    neus_upsample_kernel<<<blocks, 256, 0, stream>>>(
        rays_o, rays_d, z_vals, sdf, inv_s, out, n_rays);
}

// Round 16
// 113.039 us; speedup vs baseline: 1.0126x; 1.0126x over previous
//
#include <hip/hip_runtime.h>

// 4 rays per wave: 16 lanes/ray, 4 consecutive samples per lane (R7 base).
// R8: analytic inverse scatter. R9: fused affine scan — NEUTRAL.
// R17/R18: multipass diagnostics: VALUBusy 83%, VGPR 28, FETCH 34.8MB,
//   LDS conflicts minor => VALU-ISSUE-BOUND; occupancy/memory not limiting.
//   Calibration: ~0.027us per 2-cy op removed; trans ops ~4x.
// R19: exp2 fold + uniform-dz — WIN 114.54->113.78 (matched op model).
// R20: 8 lanes/ray geometry — REGRESSION 114.47 (masks+codegen ate the
//   fixed-cost saving). REVERTED to 16x4 geometry.
// R21: RATIO-SIGMOID. alpha = (pcf-ncf+e)/(pcf+e) with pcf=1/(1+A),
//   ncf=1/(1+B) is multiplied through by Q=(1+A)(1+B):
//     alpha = ((B-A) + eQ) / ((1+B) + eQ)
//   Exact (verified at: both-saturated eQ/eQ; A==B identical-to-ref; B>=A
//   since cosv<=0 => alpha in [0,1)). Eliminates 2 of 3 rcp per sample
//   (trans is quarter-rate). exp2 args clamped at 60: A,B<=1.15e18 keeps
//   Q finite; beyond, pcf<9e-19 << e=1e-5 — inert. Arg math folded:
//   smid=(sv+sv')*(0.5*s2), cs=cosv*(hd_c*s2), args=smid-+cs.
//   Est -24 units/lane => -0.5..-0.9us.
// R22-R24: resubmits of R21 — GPU acquisition timed out each time; R21
//   never measured. Audit complete (cs>=0, barg>=aarg, degenerate cases
//   match reference). No source change.

template<int CTRL, int RM>
__device__ __forceinline__ float dpp_movf(float old, float x) {
    return __int_as_float(__builtin_amdgcn_update_dpp(
        __float_as_int(old), __float_as_int(x), CTRL, RM, 0xF, false));
}
template<int CTRL, int RM>
__device__ __forceinline__ int dpp_movi(int old, int x) {
    return __builtin_amdgcn_update_dpp(old, x, CTRL, RM, 0xF, false);
}
// row_shr:N = 0x110|N (row = 16 lanes), wave_shl:1 = 0x130 (validated R1-R20).
__device__ __forceinline__ float fast_rcp(float x) { return __builtin_amdgcn_rcpf(x); }
__device__ __forceinline__ float bperm(float x, int srclane) {
    return __int_as_float(__builtin_amdgcn_ds_bpermute(srclane << 2, __float_as_int(x)));
}

__global__ __launch_bounds__(256, 8) void neus_upsample_kernel(
    const float* __restrict__ rays_o,
    const float* __restrict__ rays_d,
    const float* __restrict__ z_vals,
    const float* __restrict__ sdf,
    const int*   __restrict__ inv_s_ptr,
    float*       __restrict__ out,
    int n_rays)
{
    __shared__ float cdf_s[16][68];   // cdf per block-ray slot (stride-padded)
    __shared__ int   mark_s[16][64];  // scatter slots

    const int tid  = threadIdx.x;
    const int lane = tid & 63;
    const int L    = lane & 15;       // lane within ray
    const int slot = tid >> 4;        // block ray slot 0..15
    const int ray  = blockIdx.x * 16 + slot;
    if (ray >= n_rays) return;        // n_rays % 16 == 0; no __syncthreads used

    // init early - LDS store latency hides under the exp chain below.
    *(int4*)(&mark_s[slot][4 * L]) = make_int4(0, 0, 0, 0);

    const float inv_s = (float)inv_s_ptr[0];
    const float s2 = -1.4426950408889634f * inv_s;   // exp2 scale (R19)

    // ---- loads: 4 consecutive samples per lane ----
    const float4 zc = *(const float4*)(z_vals + ray * 64 + 4 * L);
    const float4 sc = *(const float4*)(sdf    + ray * 64 + 4 * L);
    const float ox = rays_o[ray*3+0], oy = rays_o[ray*3+1], oz = rays_o[ray*3+2];
    const float dx = rays_d[ray*3+0], dy = rays_d[ray*3+1], dz_ = rays_d[ray*3+2];
    const float a  = ox*ox + oy*oy + oz*oz;
    const float b2 = 2.0f * (ox*dx + oy*dy + oz*dz_);

    // sample 4L+4 from lane+1 (wave_shl:1; garbage at L==15 -> masked below)
    // z4 stays DPP-EXACT: feeds the discontinuous r2<1 predicate.
    const float z4 = dpp_movf<0x130, 0xF>(zc.x, zc.x);
    const float s4 = dpp_movf<0x130, 0xF>(sc.x, sc.x);

    // scan-independent; LDS-pipe latency overlaps the exp chain.
    const float z0  = bperm(zc.x, lane & 48);
    const float z63 = bperm(zc.w, lane | 15);
    const float h   = (z63 - z0) * (1.0f / 63.0f);

    // uniform interval width (z_vals affine in index) — R19a
    const float rden = fast_rcp(h + 1e-5f);
    const float hs2  = 0.5f * s2;              // smid = (sv+sv')*hs2 = mid*s2
    const float hds2 = (0.5f * h) * s2;        // cs = cosv*hds2 = (cosv*hd)*s2

    const float zv[5] = {zc.x, zc.y, zc.z, zc.w, z4};
    const float sv[5] = {sc.x, sc.y, sc.z, sc.w, s4};

    // ---- inside-sphere predicates (exact z; discontinuous) ----
    float insf[4];
    {
        float r2a = fmaf(zv[0], zv[0] + b2, a);
        #pragma unroll
        for (int e = 0; e < 4; ++e) {
            const float r2b = fmaf(zv[e+1], zv[e+1] + b2, a);
            insf[e] = (fminf(r2a, r2b) < 1.0f) ? 1.0f : 0.0f;
            r2a = r2b;
        }
    }

    float cr[4];
    #pragma unroll
    for (int e = 0; e < 4; ++e)
        cr[e] = (sv[e+1] - sv[e]) * rden;

    // prev-interval cos: element 3 of lane-1 (row_shr:1; 0 at ray start)
    float prev = dpp_movf<0x111, 0xF>(0.0f, cr[3]);

    // ---- fused ratio-sigmoid/alpha/weight loop (R21) ----
    float t_part[4];
    float tsum = 0.0f, prun = 1.0f;
    #pragma unroll
    for (int e = 0; e < 4; ++e) {
        float cosv = fminf(prev, cr[e]); prev = cr[e];
        cosv = fminf(fmaxf(cosv, -1000.0f), 0.0f) * insf[e];
        const float smid = (sv[e] + sv[e+1]) * hs2;   // mid*s2
        const float cs   = cosv * hds2;               // c*s2  (>=0)
        const float aarg = fminf(smid - cs, 60.0f);   // pe*s2, overflow-clamped
        const float barg = fminf(smid + cs, 60.0f);   // ne*s2
        const float A  = __builtin_amdgcn_exp2f(aarg);
        const float B  = __builtin_amdgcn_exp2f(barg);
        const float oB = 1.0f + B;
        const float Q  = (1.0f + A) * oB;
        const float num = fmaf(1e-5f, Q, B - A);
        const float den = fmaf(1e-5f, Q, oB);
        const float alpha = num * fast_rcp(den);
        float awe = alpha * prun;                 // alpha * exclusive-trans
        if (e == 3) awe = (L == 15) ? 0.0f : awe; // interval 63 doesn't exist
        t_part[e] = tsum;
        tsum += awe;
        prun *= (1.0000001f - alpha);             // (1-alpha+1e-7) folded
    }

    // ---- fused affine scan over the 16-lane row (R9) ----
    // (P,S)_L = inclusive combine of (prun_l, tsum_l); identity (1,0).
    float P = prun, S = tsum;
    {
        float Psh, Ssh;
        Psh = dpp_movf<0x111,0xF>(1.0f, P); Ssh = dpp_movf<0x111,0xF>(0.0f, S);
        S = fmaf(Psh, S, Ssh); P *= Psh;
        Psh = dpp_movf<0x112,0xF>(1.0f, P); Ssh = dpp_movf<0x112,0xF>(0.0f, S);
        S = fmaf(Psh, S, Ssh); P *= Psh;
        Psh = dpp_movf<0x114,0xF>(1.0f, P); Ssh = dpp_movf<0x114,0xF>(0.0f, S);
        S = fmaf(Psh, S, Ssh); P *= Psh;
        Psh = dpp_movf<0x118,0xF>(1.0f, P); Ssh = dpp_movf<0x118,0xF>(0.0f, S);
        S = fmaf(Psh, S, Ssh); P *= Psh;
    }
    const float Sex = dpp_movf<0x111, 0xF>(0.0f, S);  // sum over lanes < L
    const float Pex = dpp_movf<0x111, 0xF>(1.0f, P);  // transmittance into lane L

    const float T    = fmaf(63.0f, 1e-5f, bperm(S, lane | 15)); // + 63 offsets
    const float rtot = fast_rcp(T);

    // ---- cdf entries C[4L..4L+3]: (Sex + Pex*t_part[e] + (4L+e)*1e-5)/T ----
    const float kbase = (float)(4 * L);
    const float Sk    = fmaf(kbase, 1e-5f, Sex);
    float4 cvec;
    cvec.x = fmaf(Pex, t_part[0], Sk)           * rtot;   // == 0 at L==0
    cvec.y = (fmaf(Pex, t_part[1], Sk) + 1e-5f) * rtot;
    cvec.z = (fmaf(Pex, t_part[2], Sk) + 2e-5f) * rtot;
    cvec.w = (fmaf(Pex, t_part[3], Sk) + 3e-5f) * rtot;   // C[63] ~= 1 at L==15
    *(float4*)(&cdf_s[slot][4 * L]) = cvec;
    __builtin_amdgcn_wave_barrier();   // order: init+cdf before scatter

    // ---- scatter: entry j covers slots k >= ceil(64*C_j - 0.5) ----
    const float Cv[4] = {cvec.x, cvec.y, cvec.z, cvec.w};
    #pragma unroll
    for (int e = 0; e < 4; ++e) {
        const int kj = (int)ceilf(fmaf(64.0f, Cv[e], -0.5f));
        if (kj < 64) atomicMax(&mark_s[slot][kj], 4 * L + e);
    }
    __builtin_amdgcn_wave_barrier();   // order: scatter before gather

    // ---- inclusive max-scan over the 64 slots ----
    const int4 m4 = *(const int4*)(&mark_s[slot][4 * L]);
    const int i0 = m4.x;
    const int i1 = max(i0, m4.y);
    const int i2 = max(i1, m4.z);
    const int i3 = max(i2, m4.w);

    int ms = i3;
    ms = max(ms, dpp_movi<0x111, 0xF>(0, ms));
    ms = max(ms, dpp_movi<0x112, 0xF>(0, ms));
    ms = max(ms, dpp_movi<0x114, 0xF>(0, ms));
    ms = max(ms, dpp_movi<0x118, 0xF>(0, ms));
    const int Mex = dpp_movi<0x111, 0xF>(0, ms);   // max over lanes < L

    // ---- bl + interpolation merged: 2 LDS reads per query ----
    const float* cp = cdf_s[slot];
    const int iv[4] = {i0, i1, i2, i3};
    float ov[4];
    #pragma unroll
    for (int e = 0; e < 4; ++e) {
        const int   b  = min(max(Mex, iv[e]), 62);
        const float u  = fmaf(kbase + (float)e, 0.015625f, 0.0078125f);
        const float cb = cp[b];
        const float ca = cp[b + 1];
        float gap = ca - cb;
        gap = (gap < 1e-5f) ? 1.0f : gap;
        const float t = (u - cb) * fast_rcp(gap);
        ov[e] = fmaf((float)b + t, h, z0);   // z0 + h*(below + t)
    }
    *(float4*)(out + ray * 64 + 4 * L) = make_float4(ov[0], ov[1], ov[2], ov[3]);
}

extern "C" void kernel_launch(void* const* d_in, const int* in_sizes, int n_in,
                              void* d_out, int out_size, void* d_ws, size_t ws_size,
                              hipStream_t stream) {
    const float* rays_o = (const float*)d_in[0];
    const float* rays_d = (const float*)d_in[1];
    const float* z_vals = (const float*)d_in[2];
    const float* sdf    = (const float*)d_in[3];
    // d_in[4] = n_importance (== 64, hardcoded)
    const int*   inv_s  = (const int*)d_in[5];
    float* out = (float*)d_out;

    const int n_rays = in_sizes[0] / 3;          // 131072
    const int blocks = (n_rays + 15) / 16;       // 16 rays per 256-thr block

    neus_upsample_kernel<<<blocks, 256, 0, stream>>>(
        rays_o, rays_d, z_vals, sdf, inv_s, out, n_rays);
}